// Round 4
// baseline (781.352 us; speedup 1.0000x reference)
//
#include <hip/hip_runtime.h>

#define HIDDEN 4096
#define INTER  11008
#define MTOK   128          // B*S
#define NMERG  (2*INTER)    // 22016
#define KS1    4            // stage-1 K-split (bf16 partials, 22.5 MB)
#define KS2    8            // stage-2 K-split (fp32 partials, 16.8 MB)
#define BKF    256          // floats per chunk per row (1 KB contiguous per instr)

typedef short          short8  __attribute__((ext_vector_type(8)));
typedef unsigned short ushort8 __attribute__((ext_vector_type(8)));
typedef float          f32x16  __attribute__((ext_vector_type(16)));
#define AS1 __attribute__((address_space(1)))
#define AS3 __attribute__((address_space(3)))

static __device__ __forceinline__ unsigned short f2bf_rne(float f) {
    unsigned u = __builtin_bit_cast(unsigned, f);
    u += 0x7FFFu + ((u >> 16) & 1u);
    return (unsigned short)(u >> 16);
}
static __device__ __forceinline__ float bf2f(unsigned short b) {
    unsigned u = (unsigned)b << 16;
    return __builtin_bit_cast(float, u);
}
// pack two fp32 -> bf16x2 by truncation (exact for integer-valued weights)
static __device__ __forceinline__ int pk2(float lo, float hi) {
    return (int)__builtin_amdgcn_perm(__builtin_bit_cast(unsigned, hi),
                                      __builtin_bit_cast(unsigned, lo),
                                      0x07060302u);
}

// ---- x fp32 -> bf16 in MFMA A-fragment order (32x32x16) ----
// A2[((kstep*4+ms)*64+lane)*8 + j] = bf16(x[ms*32+(lane&31)][kstep*16+(lane>>5)*8+j])
__global__ void cvt_x_k(const float* __restrict__ x, unsigned short* __restrict__ A2) {
    int f = blockIdx.x * 256 + threadIdx.x;
    int lane = f & 63, w = f >> 6;
    int kstep = w >> 2, ms = w & 3;
    int m = ms * 32 + (lane & 31);
    int k = kstep * 16 + (lane >> 5) * 8;
    const float* src = x + (size_t)m * HIDDEN + k;
    float4 v0 = *(const float4*)(src);
    float4 v1 = *(const float4*)(src + 4);
    ushort8 o;
    o[0] = f2bf_rne(v0.x); o[1] = f2bf_rne(v0.y); o[2] = f2bf_rne(v0.z); o[3] = f2bf_rne(v0.w);
    o[4] = f2bf_rne(v1.x); o[5] = f2bf_rne(v1.y); o[6] = f2bf_rne(v1.z); o[7] = f2bf_rne(v1.w);
    *(ushort8*)(A2 + (size_t)f * 8) = o;
}

// ---- wave-decoupled dequant GEMM partial ----
// Each WAVE independently computes 32 output cols (weight rows) x all 128 m for one K-chunk.
// Weight rows streamed in contiguous 1KB-per-instruction chunks into a wave-private 32KB
// LDS buffer (rotation by row idx inside the 1KB keeps contiguity, spreads read banks).
// NO __syncthreads in the loop: same-wave produce/consume with explicit s_waitcnt.
template<bool OBF16>
__global__ __launch_bounds__(128) void gemm_k(
    const unsigned short* __restrict__ A2,
    const float* __restrict__ B0, const float* __restrict__ B1, int nhalf,
    void* __restrict__ part, int K, int N, int ntiles, int nChunksTot, int ksplit)
{
    __shared__ __align__(16) char lds[2][32 * 1024];
    const int lane = threadIdx.x & 63;
    const int wsl  = threadIdx.x >> 6;
    const int wid  = blockIdx.x * 2 + wsl;
    const int ntile = wid % ntiles;
    const int ks    = wid / ntiles;
    const int n0    = ntile * 32;
    const int cbeg  = (ks * nChunksTot) / ksplit;
    const int cend  = ((ks + 1) * nChunksTot) / ksplit;
    char* buf = lds[wsl];

    // tile fully inside one weight matrix (nhalf multiple of 32)
    const float* bbase = (n0 < nhalf) ? (B0 + (size_t)n0 * K)
                                      : (B1 + (size_t)(n0 - nhalf) * K);
    const size_t rowbytes = (size_t)K * 4;

    f32x16 acc[4];
#pragma unroll
    for (int t = 0; t < 4; ++t)
#pragma unroll
        for (int r = 0; r < 16; ++r) acc[t][r] = 0.f;

    const int r     = lane & 31;     // tile-local weight row this lane consumes
    const int khalf = lane >> 5;

    for (int c = cbeg; c < cend; ++c) {
        // WAR: all ds_reads of previous chunk must have completed
        __builtin_amdgcn_s_waitcnt(0xC07F);   // lgkmcnt(0)
        const char* cb = (const char*)bbase + (size_t)c * (BKF * 4);
#pragma unroll
        for (int i = 0; i < 32; ++i) {
            // instr i stages row i: contiguous 1KB, atoms rotated by i within the 1KB
            int soff = ((lane + i) & 63) * 16;
            __builtin_amdgcn_global_load_lds(
                (const AS1 unsigned*)(cb + (size_t)i * rowbytes + soff),
                (AS3 unsigned*)(buf + i * 1024), 16, 0, 0);
        }
        // RAW: staged data must have landed
        __builtin_amdgcn_s_waitcnt(0x0F70);   // vmcnt(0)

#pragma unroll
        for (int t = 0; t < 16; ++t) {
            int a0 = t * 4 + khalf * 2;                 // first 16B atom of this lane's 8 floats
            int s0 = (a0 - r) & 63;
            int s1 = (a0 + 1 - r) & 63;
            float4 v0 = *(const float4*)(buf + r * 1024 + s0 * 16);
            float4 v1 = *(const float4*)(buf + r * 1024 + s1 * 16);
            int4 bi;
            bi.x = pk2(v0.x, v0.y); bi.y = pk2(v0.z, v0.w);
            bi.z = pk2(v1.x, v1.y); bi.w = pk2(v1.z, v1.w);
            short8 bf = __builtin_bit_cast(short8, bi);
            int kg = c * 16 + t;                        // global 16-k step index
#pragma unroll
            for (int ms = 0; ms < 4; ++ms) {
                short8 af = *(const short8*)(A2 + ((size_t)(kg * 4 + ms) * 64 + lane) * 8);
                acc[ms] = __builtin_amdgcn_mfma_f32_32x32x16_bf16(af, bf, acc[ms], 0, 0, 0);
            }
        }
    }

    // C/D layout: col=lane&31, row=(r&3)+8*(r>>2)+4*(lane>>5)
    const int n = n0 + r;
#pragma unroll
    for (int ms = 0; ms < 4; ++ms)
#pragma unroll
        for (int rr = 0; rr < 16; ++rr) {
            int m = ms * 32 + (rr & 3) + 8 * (rr >> 2) + 4 * khalf;
            size_t idx = ((size_t)ks * MTOK + m) * (size_t)N + n;
            if (OBF16) ((unsigned short*)part)[idx] = f2bf_rne(acc[ms][rr]);
            else       ((float*)part)[idx] = acc[ms][rr];
        }
}

// ---- combine KS1 bf16 partials, scale, SwiGLU -> h in fragment order ----
__global__ void swiglu_k(const unsigned short* __restrict__ p1,  // [KS1][MTOK][NMERG] bf16
                         const float* __restrict__ s1, const float* __restrict__ s3,
                         unsigned short* __restrict__ h2)        // fragment-ordered, K=INTER
{
    int f = blockIdx.x * 256 + threadIdx.x;
    int lane = f & 63, w = f >> 6;
    int kstep = w >> 2, ms = w & 3;
    int m = ms * 32 + (lane & 31);
    int j = kstep * 16 + (lane >> 5) * 8;
    float up[8], gt[8];
#pragma unroll
    for (int e = 0; e < 8; ++e) { up[e] = 0.f; gt[e] = 0.f; }
#pragma unroll
    for (int ks = 0; ks < KS1; ++ks) {
        const unsigned short* pu = p1 + ((size_t)ks * MTOK + m) * NMERG + j;
        ushort8 u = *(const ushort8*)(pu);
        ushort8 g = *(const ushort8*)(pu + INTER);
#pragma unroll
        for (int e = 0; e < 8; ++e) { up[e] += bf2f(u[e]); gt[e] += bf2f(g[e]); }
    }
    float4 c1a = *(const float4*)(s1 + j), c1b = *(const float4*)(s1 + j + 4);
    float4 c3a = *(const float4*)(s3 + j), c3b = *(const float4*)(s3 + j + 4);
    float c1[8] = {c1a.x, c1a.y, c1a.z, c1a.w, c1b.x, c1b.y, c1b.z, c1b.w};
    float c3[8] = {c3a.x, c3a.y, c3a.z, c3a.w, c3b.x, c3b.y, c3b.z, c3b.w};
    ushort8 o;
#pragma unroll
    for (int e = 0; e < 8; ++e) {
        float u = up[e] * c1[e], g = gt[e] * c3[e];
        o[e] = f2bf_rne(g * u / (1.f + __expf(-u)));
    }
    *(ushort8*)(h2 + (size_t)f * 8) = o;
}

// ---- reduce KS2 fp32 partials, scale by w2_s ----
__global__ void reduce_k(const float* __restrict__ p, const float* __restrict__ s2,
                         float* __restrict__ out)
{
    int i = (blockIdx.x * 256 + threadIdx.x) * 4;
    float4 acc = *(const float4*)(p + i);
#pragma unroll
    for (int s = 1; s < KS2; ++s) {
        float4 v = *(const float4*)(p + (size_t)s * MTOK * HIDDEN + i);
        acc.x += v.x; acc.y += v.y; acc.z += v.z; acc.w += v.w;
    }
    int ncol = i & (HIDDEN - 1);
    float4 sc = *(const float4*)(s2 + ncol);
    acc.x *= sc.x; acc.y *= sc.y; acc.z *= sc.z; acc.w *= sc.w;
    *(float4*)(out + i) = acc;
}

extern "C" void kernel_launch(void* const* d_in, const int* in_sizes, int n_in,
                              void* d_out, int out_size, void* d_ws, size_t ws_size,
                              hipStream_t stream) {
    const float* x   = (const float*)d_in[0];
    const float* w1q = (const float*)d_in[1];
    const float* w1s = (const float*)d_in[2];
    const float* w3q = (const float*)d_in[3];
    const float* w3s = (const float*)d_in[4];
    const float* w2q = (const float*)d_in[5];
    const float* w2s = (const float*)d_in[6];
    float* out = (float*)d_out;

    char* ws = (char*)d_ws;
    unsigned short* xb2 = (unsigned short*)ws;                 // 1 MB   fragment-ordered x
    unsigned short* h2  = (unsigned short*)(ws + (1u << 20));  // 2.75 MB fragment-ordered h
    void* part          = (void*)(ws + (4u << 20));            // <=22.5 MB partials (reused)

    // 1) x -> bf16 fragments
    cvt_x_k<<<MTOK * HIDDEN / 8 / 256, 256, 0, stream>>>(x, xb2);
    // 2) up/gate: merged [w1;w3], N=22016 -> 688 wave-tiles, K=4096 (16 chunks), K-split 4
    gemm_k<true><<<688 * KS1 / 2, 128, 0, stream>>>(
        xb2, w1q, w3q, INTER, part, HIDDEN, NMERG, NMERG / 32, HIDDEN / BKF, KS1);
    // 3) SwiGLU -> h fragments
    swiglu_k<<<MTOK * INTER / 8 / 256, 256, 0, stream>>>(
        (const unsigned short*)part, w1s, w3s, h2);
    // 4) out: w2, N=4096 -> 128 wave-tiles, K=11008 (43 chunks), K-split 8
    gemm_k<false><<<128 * KS2 / 2, 128, 0, stream>>>(
        h2, w2q, w2q, 1 << 30, part, INTER, HIDDEN, HIDDEN / 32, INTER / BKF, KS2);
    // 5) reduce + scale
    reduce_k<<<MTOK * HIDDEN / 4 / 256, 256, 0, stream>>>(
        (const float*)part, w2s, out);
}

// Round 5
// 570.868 us; speedup vs baseline: 1.3687x; 1.3687x over previous
//
#include <hip/hip_runtime.h>

#define HIDDEN 4096
#define INTER  11008
#define MTOK   128          // B*S
#define NMERG  (2*INTER)    // 22016
#define KS1    8            // stage-1 windows of 512 k
#define KS2    22           // stage-2: 21 full + 1 tail window

typedef short          short8  __attribute__((ext_vector_type(8)));
typedef unsigned short ushort8 __attribute__((ext_vector_type(8)));
typedef float          f32x16  __attribute__((ext_vector_type(16)));

static __device__ __forceinline__ unsigned short f2bf_rne(float f) {
    unsigned u = __builtin_bit_cast(unsigned, f);
    u += 0x7FFFu + ((u >> 16) & 1u);
    return (unsigned short)(u >> 16);
}
static __device__ __forceinline__ float bf2f(unsigned short b) {
    unsigned u = (unsigned)b << 16;
    return __builtin_bit_cast(float, u);
}
// pack two fp32 -> bf16x2 by truncation (exact for integer-valued weights)
static __device__ __forceinline__ int pk2(float lo, float hi) {
    return (int)__builtin_amdgcn_perm(__builtin_bit_cast(unsigned, hi),
                                      __builtin_bit_cast(unsigned, lo),
                                      0x07060302u);
}

// ---- x fp32 -> bf16 in MFMA A-fragment order (32x32x16) ----
__global__ void cvt_x_k(const float* __restrict__ x, unsigned short* __restrict__ A2) {
    int f = blockIdx.x * 256 + threadIdx.x;
    int lane = f & 63, w = f >> 6;
    int kstep = w >> 2, ms = w & 3;
    int m = ms * 32 + (lane & 31);
    int k = kstep * 16 + (lane >> 5) * 8;
    const float* src = x + (size_t)m * HIDDEN + k;
    float4 v0 = *(const float4*)(src);
    float4 v1 = *(const float4*)(src + 4);
    ushort8 o;
    o[0] = f2bf_rne(v0.x); o[1] = f2bf_rne(v0.y); o[2] = f2bf_rne(v0.z); o[3] = f2bf_rne(v0.w);
    o[4] = f2bf_rne(v1.x); o[5] = f2bf_rne(v1.y); o[6] = f2bf_rne(v1.z); o[7] = f2bf_rne(v1.w);
    *(ushort8*)(A2 + (size_t)f * 8) = o;
}

// ---- window-staged dequant GEMM partial ----
// Block (512 thr, 8 waves) = one (32-row n-tile) x (512-k window). Stage 64KB of weight
// rows into LDS with LONG contiguous runs (each wave walks 4 whole rows, 1KB/instr),
// one barrier, waves split (ms x k-half) over MFMA, LDS cross-wave reduce, bf16 partial out.
template<int NKG>   // k-groups of 16 in window: 32 (full 512k) or 16 (256k tail)
__global__ __launch_bounds__(512) void gemm_k(
    const unsigned short* __restrict__ A2,
    const float* __restrict__ B0, const float* __restrict__ B1, int nhalf,
    unsigned short* __restrict__ part, int K, int N, int ksbase)
{
    __shared__ __align__(16) char lds[65536];
    const int t    = threadIdx.x;
    const int lane = t & 63;
    const int w    = t >> 6;
    const int n0   = blockIdx.x * 32;
    const int ksf  = ksbase + blockIdx.y;
    const int kbeg = ksf * 512;
    const int rowb = NKG * 64;            // LDS bytes per row (2048 or 1024)
    const int lpr  = NKG / 16;            // 1KB loads per row (2 or 1)

    // ---- stage: wave w walks rows 4w..4w+3 contiguously ----
    const float* bb = ((n0 < nhalf) ? (B0 + (size_t)n0 * K)
                                    : (B1 + (size_t)(n0 - nhalf) * K)) + kbeg;
#pragma unroll
    for (int j = 0; j < 4 * lpr; ++j) {
        int r    = 4 * w + ((lpr == 2) ? (j >> 1) : j);
        int half = (lpr == 2) ? (j & 1) : 0;
        int atom = half * 64 + lane;
        float4 v = *(const float4*)((const char*)bb + (size_t)r * (K * 4)
                                    + half * 1024 + lane * 16);
        *(float4*)(lds + r * rowb + ((atom ^ (r & 7)) * 16)) = v;
    }
    __syncthreads();

    // ---- compute: wave (ms, h) ----
    const int ms = w >> 1, h = w & 1;
    const int half = NKG / 2;
    const int r  = lane & 31;
    const int kh = lane >> 5;
    f32x16 acc;
#pragma unroll
    for (int i = 0; i < 16; ++i) acc[i] = 0.f;

#pragma unroll
    for (int kg = h * half; kg < h * half + half; ++kg) {
        int a0 = kg * 4 + kh * 2;
        float4 v0 = *(const float4*)(lds + r * rowb + ((a0 ^ (r & 7)) * 16));
        float4 v1 = *(const float4*)(lds + r * rowb + (((a0 + 1) ^ (r & 7)) * 16));
        int4 bi;
        bi.x = pk2(v0.x, v0.y); bi.y = pk2(v0.z, v0.w);
        bi.z = pk2(v1.x, v1.y); bi.w = pk2(v1.z, v1.w);
        short8 bf = __builtin_bit_cast(short8, bi);
        int kstep = (kbeg >> 4) + kg;
        short8 af = *(const short8*)(A2 + ((size_t)(kstep * 4 + ms) * 64 + lane) * 8);
        acc = __builtin_amdgcn_mfma_f32_32x32x16_bf16(af, bf, acc, 0, 0, 0);
    }
    __syncthreads();    // all LDS weight reads done; reuse LDS for reduction

    // ---- dump acc: slot stride 72B to spread banks ----
    {
        char* rb = lds + (size_t)(w * 64 + lane) * 72;
#pragma unroll
        for (int q = 0; q < 4; ++q)
            *(float4*)(rb + q * 16) = *(const float4*)((const float*)&acc + q * 4);
    }
    __syncthreads();

    // ---- reduce over h-pairs, write bf16 partials ----
    const int msp = t >> 7;
    const int lp  = (t >> 1) & 63;
    const int qp  = t & 1;
    const int n   = n0 + (lp & 31);
    const int khp = lp >> 5;
#pragma unroll
    for (int qq = 0; qq < 2; ++qq) {
        int q = qp * 2 + qq;
        float4 s0 = *(const float4*)(lds + (size_t)(((msp * 2 + 0) * 64 + lp)) * 72 + q * 16);
        float4 s1 = *(const float4*)(lds + (size_t)(((msp * 2 + 1) * 64 + lp)) * 72 + q * 16);
        float s[4] = {s0.x + s1.x, s0.y + s1.y, s0.z + s1.z, s0.w + s1.w};
#pragma unroll
        for (int e = 0; e < 4; ++e) {
            int m = msp * 32 + e + 8 * q + 4 * khp;
            part[((size_t)ksf * MTOK + m) * (size_t)N + n] = f2bf_rne(s[e]);
        }
    }
}

// ---- combine KS1 bf16 partials, scale, SwiGLU -> h in fragment order ----
__global__ void swiglu_k(const unsigned short* __restrict__ p1,  // [KS1][MTOK][NMERG] bf16
                         const float* __restrict__ s1, const float* __restrict__ s3,
                         unsigned short* __restrict__ h2)        // fragment-ordered, K=INTER
{
    int f = blockIdx.x * 256 + threadIdx.x;
    int lane = f & 63, w = f >> 6;
    int kstep = w >> 2, ms = w & 3;
    int m = ms * 32 + (lane & 31);
    int j = kstep * 16 + (lane >> 5) * 8;
    float up[8], gt[8];
#pragma unroll
    for (int e = 0; e < 8; ++e) { up[e] = 0.f; gt[e] = 0.f; }
#pragma unroll
    for (int ks = 0; ks < KS1; ++ks) {
        const unsigned short* pu = p1 + ((size_t)ks * MTOK + m) * NMERG + j;
        ushort8 u = *(const ushort8*)(pu);
        ushort8 g = *(const ushort8*)(pu + INTER);
#pragma unroll
        for (int e = 0; e < 8; ++e) { up[e] += bf2f(u[e]); gt[e] += bf2f(g[e]); }
    }
    float4 c1a = *(const float4*)(s1 + j), c1b = *(const float4*)(s1 + j + 4);
    float4 c3a = *(const float4*)(s3 + j), c3b = *(const float4*)(s3 + j + 4);
    float c1[8] = {c1a.x, c1a.y, c1a.z, c1a.w, c1b.x, c1b.y, c1b.z, c1b.w};
    float c3[8] = {c3a.x, c3a.y, c3a.z, c3a.w, c3b.x, c3b.y, c3b.z, c3b.w};
    ushort8 o;
#pragma unroll
    for (int e = 0; e < 8; ++e) {
        float u = up[e] * c1[e], g = gt[e] * c3[e];
        o[e] = f2bf_rne(g * u / (1.f + __expf(-u)));
    }
    *(ushort8*)(h2 + (size_t)f * 8) = o;
}

// ---- reduce KS2 bf16 partials, scale by w2_s ----
__global__ void reduce_k(const unsigned short* __restrict__ p, const float* __restrict__ s2,
                         float* __restrict__ out)
{
    int i = (blockIdx.x * 256 + threadIdx.x) * 4;
    float a[4] = {0.f, 0.f, 0.f, 0.f};
#pragma unroll
    for (int s = 0; s < KS2; ++s) {
        ushort4 v = *(const ushort4*)(p + (size_t)s * MTOK * HIDDEN + i);
        a[0] += bf2f(v.x); a[1] += bf2f(v.y); a[2] += bf2f(v.z); a[3] += bf2f(v.w);
    }
    int ncol = i & (HIDDEN - 1);
    float4 sc = *(const float4*)(s2 + ncol);
    float4 o = {a[0] * sc.x, a[1] * sc.y, a[2] * sc.z, a[3] * sc.w};
    *(float4*)(out + i) = o;
}

extern "C" void kernel_launch(void* const* d_in, const int* in_sizes, int n_in,
                              void* d_out, int out_size, void* d_ws, size_t ws_size,
                              hipStream_t stream) {
    const float* x   = (const float*)d_in[0];
    const float* w1q = (const float*)d_in[1];
    const float* w1s = (const float*)d_in[2];
    const float* w3q = (const float*)d_in[3];
    const float* w3s = (const float*)d_in[4];
    const float* w2q = (const float*)d_in[5];
    const float* w2s = (const float*)d_in[6];
    float* out = (float*)d_out;

    char* ws = (char*)d_ws;
    unsigned short* xb2 = (unsigned short*)ws;                 // 1 MB   fragment-ordered x
    unsigned short* h2  = (unsigned short*)(ws + (1u << 20));  // 2.75 MB fragment-ordered h
    unsigned short* part = (unsigned short*)(ws + (4u << 20)); // <=45.1 MB bf16 partials (reused)

    // 1) x -> bf16 fragments
    cvt_x_k<<<MTOK * HIDDEN / 8 / 256, 256, 0, stream>>>(x, xb2);
    // 2) up/gate: merged [w1;w3], 688 n-tiles x 8 windows of 512k
    gemm_k<32><<<dim3(NMERG / 32, KS1), 512, 0, stream>>>(
        xb2, w1q, w3q, INTER, part, HIDDEN, NMERG, 0);
    // 3) SwiGLU -> h fragments
    swiglu_k<<<MTOK * INTER / 8 / 256, 256, 0, stream>>>(part, w1s, w3s, h2);
    // 4) out: w2, 128 n-tiles x (21 full + 1 tail) windows
    gemm_k<32><<<dim3(HIDDEN / 32, KS2 - 1), 512, 0, stream>>>(
        h2, w2q, w2q, 1 << 30, part, INTER, HIDDEN, 0);
    gemm_k<16><<<dim3(HIDDEN / 32, 1), 512, 0, stream>>>(
        h2, w2q, w2q, 1 << 30, part, INTER, HIDDEN, KS2 - 1);
    // 5) reduce + scale
    reduce_k<<<MTOK * HIDDEN / 4 / 256, 256, 0, stream>>>(part, w2s, out);
}